// Round 6
// baseline (4494.054 us; speedup 1.0000x reference)
//
#include <hip/hip_runtime.h>

#define T_LEN 16384
#define BATCH 32
#define HID 32
#define L2E 1.44269504088896340736f

#if __has_builtin(__builtin_amdgcn_exp2f)
#define EXP2F(x) __builtin_amdgcn_exp2f(x)
#else
#define EXP2F(x) __exp2f(x)
#endif
#if __has_builtin(__builtin_amdgcn_rcpf)
#define RCPF(x) __builtin_amdgcn_rcpf(x)
#else
#define RCPF(x) (1.0f / (x))
#endif

__device__ __forceinline__ float rlane(float v, int lane) {
    return __int_as_float(__builtin_amdgcn_readlane(__float_as_int(v), lane));
}

// Cross-half exchange (lower->upper), VALU pipe. HW convention established
// round 4/5: builtin returns {vdst_new, vsrc_new}; instruction swaps vdst
// lanes[32:63] with vsrc lanes[0:31]; with both args = v, r.x has
// lanes 32-63 = old lanes 0-31. (r.y was wrong: absmax 0.34 in round 4.)
__device__ __forceinline__ float xhalf_lo_to_hi(float v) {
#if __has_builtin(__builtin_amdgcn_permlane32_swap)
    typedef unsigned u2_t __attribute__((ext_vector_type(2)));
    u2_t r = __builtin_amdgcn_permlane32_swap(__float_as_uint(v), __float_as_uint(v),
                                              false, false);
    return __uint_as_float(r.x);
#else
    return __shfl_xor(v, 32, 64);
#endif
}

// One wave per batch. Lane j<32: gates (i_j, g_j); lane 32+j: (f_j, o_j) +
// state (c_j, h_j). h broadcast via v_readlane -> SGPRs.
//
// Round 6 change: asm-pin Wa/Wb into VGPRs (NO amdgpu_waves_per_eu attr —
// round 2 confounded the two; arithmetic says the ~250 cyc/step of exposed
// L1 waitcnt from small-batch W reloads at VGPR=48 is the dominant stall,
// so residency should win and round-2's regression was the attr).
// Also: gate weights pre-scaled by -log2e*{1,2} so each activation is
// rcp(1+exp2(z')) with no dependent v_mul on the chain.
__global__ __launch_bounds__(64, 1)
void lstm_seq_kernel(const float* __restrict__ x,
                     const float* __restrict__ W_ih,
                     const float* __restrict__ W_hh,
                     const float* __restrict__ b_ih,
                     const float* __restrict__ b_hh,
                     const float* __restrict__ W_out,
                     const float* __restrict__ b_out,
                     float* __restrict__ out)
{
    const int b    = blockIdx.x;
    const int lane = threadIdx.x;
    const int j    = lane & 31;
    const bool upper = (lane >= 32);

    // torch gate order in W_ih/W_hh rows: [0,32)=i [32,64)=f [64,96)=g [96,128)=o
    const int rowA = upper ? (32 + j) : j;        // f : i   (both sigmoid)
    const int rowB = upper ? (96 + j) : (64 + j); // o : g   (sigmoid : tanh)

    // Activation pre-scale: A = sigmoid(za) = rcp(1+exp2(-L2E*za)); fold
    // -L2E into the A-row. B-gate: tanh (lower) uses -2*L2E, sigmoid (upper)
    // uses -L2E.
    const float sclA = -L2E;
    const float sclB = upper ? -L2E : (-2.0f * L2E);

    float Wa[HID], Wb[HID];
    const float4* Whh4 = reinterpret_cast<const float4*>(W_hh);
    #pragma unroll
    for (int q = 0; q < 8; ++q) {
        float4 va = Whh4[rowA * 8 + q];
        Wa[4*q+0] = sclA*va.x; Wa[4*q+1] = sclA*va.y; Wa[4*q+2] = sclA*va.z; Wa[4*q+3] = sclA*va.w;
        float4 vb = Whh4[rowB * 8 + q];
        Wb[4*q+0] = sclB*vb.x; Wb[4*q+1] = sclB*vb.y; Wb[4*q+2] = sclB*vb.z; Wb[4*q+3] = sclB*vb.w;
    }
    // Pin scaled weights into VGPRs: asm output is opaque -> compiler cannot
    // rematerialize/reload them inside the loop (defeats the VGPR=48 heuristic
    // that caused per-step L1 reload stalls).
    #pragma unroll
    for (int k = 0; k < HID; ++k) {
        asm("" : "+v"(Wa[k]), "+v"(Wb[k]));
    }

    const float wihA = sclA * W_ih[rowA];
    const float wihB = sclB * W_ih[rowB];
    const float bA = sclA * (b_ih[rowA] + b_hh[rowA]);
    const float bB = sclB * (b_ih[rowB] + b_hh[rowB]);

    // B-gate shaping: Bv = r*mB + aB  (tanh: 2r-1, sigmoid: r)
    const float mB = upper ? 1.0f : 2.0f;
    const float aB = upper ? 0.0f : -1.0f;

    const float wout = W_out[j];
    const float bout = b_out[0];

    __shared__ float phist[64 * 33];

    float hs[HID];
    #pragma unroll
    for (int k = 0; k < HID; ++k) hs[k] = 0.0f;
    float c = 0.0f;

    const float* xb = x + (size_t)b * T_LEN;
    float*       yb = out + (size_t)b * T_LEN;

    float xv = xb[lane];  // 64 timesteps of x per lane-chunk

    for (int t0 = 0; t0 < T_LEN; t0 += 64) {
        float xv_next = (t0 + 64 < T_LEN) ? xb[t0 + 64 + lane] : 0.0f;

        #pragma unroll 4
        for (int s = 0; s < 64; ++s) {
            const float xs = rlane(xv, s);
            // 4-way split accumulators: 8 independent 8-deep fmac chains
            float za0 = fmaf(xs, wihA, bA), za1 = 0.0f, za2 = 0.0f, za3 = 0.0f;
            float zb0 = fmaf(xs, wihB, bB), zb1 = 0.0f, zb2 = 0.0f, zb3 = 0.0f;
            #pragma unroll
            for (int q = 0; q < 8; ++q) {
                za0 = fmaf(hs[q     ], Wa[q     ], za0);
                za1 = fmaf(hs[q +  8], Wa[q +  8], za1);
                za2 = fmaf(hs[q + 16], Wa[q + 16], za2);
                za3 = fmaf(hs[q + 24], Wa[q + 24], za3);
                zb0 = fmaf(hs[q     ], Wb[q     ], zb0);
                zb1 = fmaf(hs[q +  8], Wb[q +  8], zb1);
                zb2 = fmaf(hs[q + 16], Wb[q + 16], zb2);
                zb3 = fmaf(hs[q + 24], Wb[q + 24], zb3);
            }
            const float za = (za0 + za1) + (za2 + za3);   // pre-scaled
            const float zb = (zb0 + zb1) + (zb2 + zb3);   // pre-scaled

            const float A  = RCPF(1.0f + EXP2F(za));      // sigmoid(i / f)
            const float r  = RCPF(1.0f + EXP2F(zb));
            const float Bv = fmaf(r, mB, aB);             // tanh(g) : sigmoid(o)

            const float u  = A * Bv;                      // sig(i)*tanh(g) (lower)
            const float tu = xhalf_lo_to_hi(u);           // VALU cross-half ship

            c = fmaf(A, c, tu);                           // sig(f)*c + u (upper)
            const float th = fmaf(2.0f, RCPF(1.0f + EXP2F(-2.0f * L2E * c)), -1.0f);
            const float h  = Bv * th;                     // sig(o)*tanh(c)

            if (upper) phist[s * 33 + j] = h * wout;

            #pragma unroll
            for (int k = 0; k < HID; ++k) hs[k] = rlane(h, 32 + k);
        }

        __syncthreads();  // single wave: cheap; publish phist
        float acc = bout;
        #pragma unroll
        for (int k = 0; k < HID; ++k) acc += phist[lane * 33 + k];
        yb[t0 + lane] = acc;
        __syncthreads();  // protect phist before next chunk rewrites it

        xv = xv_next;
    }
}

extern "C" void kernel_launch(void* const* d_in, const int* in_sizes, int n_in,
                              void* d_out, int out_size, void* d_ws, size_t ws_size,
                              hipStream_t stream) {
    const float* x     = (const float*)d_in[0];
    const float* W_ih  = (const float*)d_in[1];
    const float* W_hh  = (const float*)d_in[2];
    const float* b_ih  = (const float*)d_in[3];
    const float* b_hh  = (const float*)d_in[4];
    const float* W_out = (const float*)d_in[5];
    const float* b_out = (const float*)d_in[6];
    float* out = (float*)d_out;

    lstm_seq_kernel<<<BATCH, 64, 0, stream>>>(x, W_ih, W_hh, b_ih, b_hh,
                                              W_out, b_out, out);
}

// Round 7
// 3742.275 us; speedup vs baseline: 1.2009x; 1.2009x over previous
//
#include <hip/hip_runtime.h>

#define T_LEN 16384
#define BATCH 32
#define HID 32
#define L2E 1.44269504088896340736f

typedef float f2 __attribute__((ext_vector_type(2)));

#if __has_builtin(__builtin_amdgcn_exp2f)
#define EXP2F(x) __builtin_amdgcn_exp2f(x)
#else
#define EXP2F(x) __exp2f(x)
#endif
#if __has_builtin(__builtin_amdgcn_rcpf)
#define RCPF(x) __builtin_amdgcn_rcpf(x)
#else
#define RCPF(x) (1.0f / (x))
#endif

__device__ __forceinline__ float rlane(float v, int lane) {
    return __int_as_float(__builtin_amdgcn_readlane(__float_as_int(v), lane));
}
__device__ __forceinline__ unsigned rlane_u(float v, int lane) {
    return (unsigned)__builtin_amdgcn_readlane(__float_as_int(v), lane);
}

// Cross-half exchange (lower->upper), VALU pipe. Convention verified r4/r5:
// builtin returns {vdst_new, vsrc_new}; r.x has lanes 32-63 = old lanes 0-31.
__device__ __forceinline__ float xhalf_lo_to_hi(float v) {
#if __has_builtin(__builtin_amdgcn_permlane32_swap)
    typedef unsigned u2_t __attribute__((ext_vector_type(2)));
    u2_t r = __builtin_amdgcn_permlane32_swap(__float_as_uint(v), __float_as_uint(v),
                                              false, false);
    return __uint_as_float(r.x);
#else
    return __shfl_xor(v, 32, 64);
#endif
}

// One wave per batch. Lane j<32: gates (i_j, g_j); lane 32+j: (f_j, o_j) +
// state (c_j, h_j). h broadcast via readlane, packed into SGPR PAIRS (SALU
// packing — off the VALU issue budget) so the dots run as v_pk_fma_f32:
// 32 packed fmas replace 64 scalar fmacs. Weights stay RAW and unpinned —
// the compiler's L1 reload (loop-invariant addresses, VMEM pipe) hides
// completely; both forced-residency variants (r2 VGPR=132, r6 scratch spill)
// measured slower than reload (r5).
__global__ __launch_bounds__(64, 1)
void lstm_seq_kernel(const float* __restrict__ x,
                     const float* __restrict__ W_ih,
                     const float* __restrict__ W_hh,
                     const float* __restrict__ b_ih,
                     const float* __restrict__ b_hh,
                     const float* __restrict__ W_out,
                     const float* __restrict__ b_out,
                     float* __restrict__ out)
{
    const int b    = blockIdx.x;
    const int lane = threadIdx.x;
    const int j    = lane & 31;
    const bool upper = (lane >= 32);

    // torch gate order in W_ih/W_hh rows: [0,32)=i [32,64)=f [64,96)=g [96,128)=o
    const int rowA = upper ? (32 + j) : j;        // f : i   (both sigmoid)
    const int rowB = upper ? (96 + j) : (64 + j); // o : g   (sigmoid : tanh)

    // W rows as float2 pairs (raw values; pairs are 8B-aligned within the row)
    f2 Wa2[16], Wb2[16];
    const f2* ra2 = reinterpret_cast<const f2*>(W_hh + (size_t)rowA * HID);
    const f2* rb2 = reinterpret_cast<const f2*>(W_hh + (size_t)rowB * HID);
    #pragma unroll
    for (int q = 0; q < 16; ++q) { Wa2[q] = ra2[q]; Wb2[q] = rb2[q]; }

    const float wihA = W_ih[rowA];
    const float wihB = W_ih[rowB];
    const float bA = b_ih[rowA] + b_hh[rowA];
    const float bB = b_ih[rowB] + b_hh[rowB];

    // B-gate activation: r = rcp(1 + exp2(-z*sB)); B = r*mB + aB
    const float sB = upper ? L2E : (2.0f * L2E);
    const float mB = upper ? 1.0f : 2.0f;
    const float aB = upper ? 0.0f : -1.0f;

    const float wout = W_out[j];
    const float bout = b_out[0];

    // phist[s][lane], stride 65: store banks (65s+l)%32=(s+l)%32 conflict-free;
    // flush read phist[l*65+32+k] banks (l+k)%32 conflict-free. Unconditional
    // store (all 64 lanes) — no exec-mask flip on the hot path.
    __shared__ float phist[64 * 65];

    // h broadcast as 16 uniform SGPR pairs {h_2q, h_2q+1}
    unsigned long long hp[16];
    #pragma unroll
    for (int q = 0; q < 16; ++q) hp[q] = 0ull;
    float c = 0.0f;

    const float* xb = x + (size_t)b * T_LEN;
    float*       yb = out + (size_t)b * T_LEN;

    float xv = xb[lane];  // 64 timesteps of x per lane-chunk

    for (int t0 = 0; t0 < T_LEN; t0 += 64) {
        float xv_next = (t0 + 64 < T_LEN) ? xb[t0 + 64 + lane] : 0.0f;

        #pragma unroll 4
        for (int s = 0; s < 64; ++s) {
            const float xs = rlane(xv, s);
            // 4-way split packed accumulators; .x = even k, .y = odd k
            f2 zA[4], zB[4];
            zA[0].x = fmaf(xs, wihA, bA); zA[0].y = 0.0f;
            zB[0].x = fmaf(xs, wihB, bB); zB[0].y = 0.0f;
            #pragma unroll
            for (int m = 1; m < 4; ++m) { zA[m] = (f2)0.0f; zB[m] = (f2)0.0f; }

            // 32 v_pk_fma_f32 (SGPR-pair h source) replace 64 scalar fmacs
            #pragma unroll
            for (int q = 0; q < 16; ++q) {
                asm("v_pk_fma_f32 %0, %1, %2, %0"
                    : "+v"(zA[q & 3]) : "s"(hp[q]), "v"(Wa2[q]));
                asm("v_pk_fma_f32 %0, %1, %2, %0"
                    : "+v"(zB[q & 3]) : "s"(hp[q]), "v"(Wb2[q]));
            }
            const f2 sA = (zA[0] + zA[1]) + (zA[2] + zA[3]);
            const f2 sBv = (zB[0] + zB[1]) + (zB[2] + zB[3]);
            const float za = sA.x + sA.y;
            const float zb = sBv.x + sBv.y;

            // A = sigmoid(za)  (i on lower, f on upper)
            const float A  = RCPF(1.0f + EXP2F(-za * L2E));
            const float r  = RCPF(1.0f + EXP2F(-zb * sB));
            const float Bv = fmaf(r, mB, aB);  // tanh(g) : sigmoid(o)

            const float u  = A * Bv;           // sig(i)*tanh(g) (lower)
            const float tu = xhalf_lo_to_hi(u);

            c = fmaf(A, c, tu);                // sig(f)*c + u (upper lanes valid)
            const float th = fmaf(2.0f, RCPF(1.0f + EXP2F(-2.0f * L2E * c)), -1.0f);
            const float h  = Bv * th;          // sig(o)*tanh(c)

            phist[s * 65 + lane] = h * wout;   // unconditional, conflict-free

            // repack h broadcast: 32 readlanes + SALU 64-bit packing
            #pragma unroll
            for (int q = 0; q < 16; ++q) {
                const unsigned lo = rlane_u(h, 32 + 2 * q);
                const unsigned hi = rlane_u(h, 32 + 2 * q + 1);
                hp[q] = (unsigned long long)lo |
                        ((unsigned long long)hi << 32);
            }
        }

        __syncthreads();  // single wave: cheap; publish phist
        float acc = bout;
        #pragma unroll
        for (int k = 0; k < HID; ++k) acc += phist[lane * 65 + 32 + k];
        yb[t0 + lane] = acc;
        __syncthreads();  // protect phist before next chunk rewrites it

        xv = xv_next;
    }
}

extern "C" void kernel_launch(void* const* d_in, const int* in_sizes, int n_in,
                              void* d_out, int out_size, void* d_ws, size_t ws_size,
                              hipStream_t stream) {
    const float* x     = (const float*)d_in[0];
    const float* W_ih  = (const float*)d_in[1];
    const float* W_hh  = (const float*)d_in[2];
    const float* b_ih  = (const float*)d_in[3];
    const float* b_hh  = (const float*)d_in[4];
    const float* W_out = (const float*)d_in[5];
    const float* b_out = (const float*)d_in[6];
    float* out = (float*)d_out;

    lstm_seq_kernel<<<BATCH, 64, 0, stream>>>(x, W_ih, W_hh, b_ih, b_hh,
                                              W_out, b_out, out);
}

// Round 8
// 3731.146 us; speedup vs baseline: 1.2045x; 1.0030x over previous
//
#include <hip/hip_runtime.h>

#define T_LEN 16384
#define BATCH 32
#define HID 32
#define L2E 1.44269504088896340736f

typedef float f2 __attribute__((ext_vector_type(2)));

#if __has_builtin(__builtin_amdgcn_exp2f)
#define EXP2F(x) __builtin_amdgcn_exp2f(x)
#else
#define EXP2F(x) __exp2f(x)
#endif
#if __has_builtin(__builtin_amdgcn_rcpf)
#define RCPF(x) __builtin_amdgcn_rcpf(x)
#else
#define RCPF(x) (1.0f / (x))
#endif

__device__ __forceinline__ float rlane(float v, int lane) {
    return __int_as_float(__builtin_amdgcn_readlane(__float_as_int(v), lane));
}
__device__ __forceinline__ unsigned rlane_u(float v, int lane) {
    return (unsigned)__builtin_amdgcn_readlane(__float_as_int(v), lane);
}

// Cross-half exchange (lower->upper), VALU pipe. Convention verified r4/r5:
// builtin returns {vdst_new, vsrc_new}; r.x has lanes 32-63 = old lanes 0-31.
__device__ __forceinline__ float xhalf_lo_to_hi(float v) {
#if __has_builtin(__builtin_amdgcn_permlane32_swap)
    typedef unsigned u2_t __attribute__((ext_vector_type(2)));
    u2_t r = __builtin_amdgcn_permlane32_swap(__float_as_uint(v), __float_as_uint(v),
                                              false, false);
    return __uint_as_float(r.x);
#else
    return __shfl_xor(v, 32, 64);
#endif
}

// r8 = r7 + amdgpu_waves_per_eu(1) MIN-ONLY (no max clamp). Tests H1:
// at VGPR=76 the 64 weight VGPRs (32 float2) can't be resident -> per-step
// L1 reloads with exposed vmcnt waits ~ the unexplained ~300 cyc/step stall.
// r2 confounded residency with the (1,1) max-clamp; r6 pins forced scratch
// spill. This is the first clean residency test on the pk structure.
__global__ __launch_bounds__(64, 1) __attribute__((amdgpu_waves_per_eu(1)))
void lstm_seq_kernel(const float* __restrict__ x,
                     const float* __restrict__ W_ih,
                     const float* __restrict__ W_hh,
                     const float* __restrict__ b_ih,
                     const float* __restrict__ b_hh,
                     const float* __restrict__ W_out,
                     const float* __restrict__ b_out,
                     float* __restrict__ out)
{
    const int b    = blockIdx.x;
    const int lane = threadIdx.x;
    const int j    = lane & 31;
    const bool upper = (lane >= 32);

    // torch gate order in W_ih/W_hh rows: [0,32)=i [32,64)=f [64,96)=g [96,128)=o
    const int rowA = upper ? (32 + j) : j;        // f : i   (both sigmoid)
    const int rowB = upper ? (96 + j) : (64 + j); // o : g   (sigmoid : tanh)

    // W rows as float2 pairs (raw values; pairs are 8B-aligned within the row)
    f2 Wa2[16], Wb2[16];
    const f2* ra2 = reinterpret_cast<const f2*>(W_hh + (size_t)rowA * HID);
    const f2* rb2 = reinterpret_cast<const f2*>(W_hh + (size_t)rowB * HID);
    #pragma unroll
    for (int q = 0; q < 16; ++q) { Wa2[q] = ra2[q]; Wb2[q] = rb2[q]; }

    const float wihA = W_ih[rowA];
    const float wihB = W_ih[rowB];
    const float bA = b_ih[rowA] + b_hh[rowA];
    const float bB = b_ih[rowB] + b_hh[rowB];

    // B-gate activation: r = rcp(1 + exp2(-z*sB)); B = r*mB + aB
    const float sB = upper ? L2E : (2.0f * L2E);
    const float mB = upper ? 1.0f : 2.0f;
    const float aB = upper ? 0.0f : -1.0f;

    const float wout = W_out[j];
    const float bout = b_out[0];

    // phist[s][lane], stride 65: store banks (s+l)%32 conflict-free;
    // flush read phist[l*65+32+k] banks (l+k)%32 conflict-free.
    __shared__ float phist[64 * 65];

    // h broadcast as 16 uniform SGPR pairs {h_2q, h_2q+1}
    unsigned long long hp[16];
    #pragma unroll
    for (int q = 0; q < 16; ++q) hp[q] = 0ull;
    float c = 0.0f;

    const float* xb = x + (size_t)b * T_LEN;
    float*       yb = out + (size_t)b * T_LEN;

    float xv = xb[lane];  // 64 timesteps of x per lane-chunk

    for (int t0 = 0; t0 < T_LEN; t0 += 64) {
        float xv_next = (t0 + 64 < T_LEN) ? xb[t0 + 64 + lane] : 0.0f;

        #pragma unroll 4
        for (int s = 0; s < 64; ++s) {
            const float xs = rlane(xv, s);
            // 4-way split packed accumulators; .x = even k, .y = odd k
            f2 zA[4], zB[4];
            zA[0].x = fmaf(xs, wihA, bA); zA[0].y = 0.0f;
            zB[0].x = fmaf(xs, wihB, bB); zB[0].y = 0.0f;
            #pragma unroll
            for (int m = 1; m < 4; ++m) { zA[m] = (f2)0.0f; zB[m] = (f2)0.0f; }

            // 32 v_pk_fma_f32 (SGPR-pair h source) replace 64 scalar fmacs
            #pragma unroll
            for (int q = 0; q < 16; ++q) {
                asm("v_pk_fma_f32 %0, %1, %2, %0"
                    : "+v"(zA[q & 3]) : "s"(hp[q]), "v"(Wa2[q]));
                asm("v_pk_fma_f32 %0, %1, %2, %0"
                    : "+v"(zB[q & 3]) : "s"(hp[q]), "v"(Wb2[q]));
            }
            const f2 sA = (zA[0] + zA[1]) + (zA[2] + zA[3]);
            const f2 sBv = (zB[0] + zB[1]) + (zB[2] + zB[3]);
            const float za = sA.x + sA.y;
            const float zb = sBv.x + sBv.y;

            // A = sigmoid(za)  (i on lower, f on upper)
            const float A  = RCPF(1.0f + EXP2F(-za * L2E));
            const float r  = RCPF(1.0f + EXP2F(-zb * sB));
            const float Bv = fmaf(r, mB, aB);  // tanh(g) : sigmoid(o)

            const float u  = A * Bv;           // sig(i)*tanh(g) (lower)
            const float tu = xhalf_lo_to_hi(u);

            c = fmaf(A, c, tu);                // sig(f)*c + u (upper lanes valid)
            const float th = fmaf(2.0f, RCPF(1.0f + EXP2F(-2.0f * L2E * c)), -1.0f);
            const float h  = Bv * th;          // sig(o)*tanh(c)

            phist[s * 65 + lane] = h * wout;   // unconditional, conflict-free

            // repack h broadcast: 32 readlanes + SALU 64-bit packing
            #pragma unroll
            for (int q = 0; q < 16; ++q) {
                const unsigned lo = rlane_u(h, 32 + 2 * q);
                const unsigned hi = rlane_u(h, 32 + 2 * q + 1);
                hp[q] = (unsigned long long)lo |
                        ((unsigned long long)hi << 32);
            }
        }

        __syncthreads();  // single wave: cheap; publish phist
        float acc = bout;
        #pragma unroll
        for (int k = 0; k < HID; ++k) acc += phist[lane * 65 + 32 + k];
        yb[t0 + lane] = acc;
        __syncthreads();  // protect phist before next chunk rewrites it

        xv = xv_next;
    }
}

extern "C" void kernel_launch(void* const* d_in, const int* in_sizes, int n_in,
                              void* d_out, int out_size, void* d_ws, size_t ws_size,
                              hipStream_t stream) {
    const float* x     = (const float*)d_in[0];
    const float* W_ih  = (const float*)d_in[1];
    const float* W_hh  = (const float*)d_in[2];
    const float* b_ih  = (const float*)d_in[3];
    const float* b_hh  = (const float*)d_in[4];
    const float* W_out = (const float*)d_in[5];
    const float* b_out = (const float*)d_in[6];
    float* out = (float*)d_out;

    lstm_seq_kernel<<<BATCH, 64, 0, stream>>>(x, W_ih, W_hh, b_ih, b_hh,
                                              W_out, b_out, out);
}

// Round 9
// 3640.054 us; speedup vs baseline: 1.2346x; 1.0250x over previous
//
#include <hip/hip_runtime.h>

#define T_LEN 16384
#define BATCH 32
#define HID 32
#define L2E 1.44269504088896340736f

typedef float f2 __attribute__((ext_vector_type(2)));

#if __has_builtin(__builtin_amdgcn_exp2f)
#define EXP2F(x) __builtin_amdgcn_exp2f(x)
#else
#define EXP2F(x) __exp2f(x)
#endif
#if __has_builtin(__builtin_amdgcn_rcpf)
#define RCPF(x) __builtin_amdgcn_rcpf(x)
#else
#define RCPF(x) (1.0f / (x))
#endif

__device__ __forceinline__ float rlane(float v, int lane) {
    return __int_as_float(__builtin_amdgcn_readlane(__float_as_int(v), lane));
}
__device__ __forceinline__ unsigned rlane_u(float v, int lane) {
    return (unsigned)__builtin_amdgcn_readlane(__float_as_int(v), lane);
}

// Cross-half exchange (lower->upper), VALU pipe. Convention verified r4/r5:
// builtin returns {vdst_new, vsrc_new}; r.x has lanes 32-63 = old lanes 0-31.
__device__ __forceinline__ float xhalf_lo_to_hi(float v) {
#if __has_builtin(__builtin_amdgcn_permlane32_swap)
    typedef unsigned u2_t __attribute__((ext_vector_type(2)));
    u2_t r = __builtin_amdgcn_permlane32_swap(__float_as_uint(v), __float_as_uint(v),
                                              false, false);
    return __uint_as_float(r.x);
#else
    return __shfl_xor(v, 32, 64);
#endif
}

// r9 = r7 PK kernel + forced weight residency + trims.
// Residency cell never tested before: waves_per_eu(1,1) [max-clamp LICENSES
// the allocator past its pressure target — r8 proved min-only doesn't] +
// asm pins [prevent re-load sinking; r6 proved pins WITHOUT the clamp spill
// to scratch]. Reload arithmetic from r8: FETCH 1134MB/16384/32 = 2.2KB per
// block-step = the ~550 floats of weight reload at VGPR=76 -> 100-200 cyc/step
// of L1/L2 bandwidth + waitcnt pacing. Goal: VGPR ~140, reloads gone.
// Trims: v_pk_mul_f32 accumulator starts (kills ~14 zero-init movs); h
// readlane/pack fused per-q into the dot (no broadcast/consume phase barrier);
// x contribution fully off-chain.
__global__ __launch_bounds__(64) __attribute__((amdgpu_waves_per_eu(1, 1)))
void lstm_seq_kernel(const float* __restrict__ x,
                     const float* __restrict__ W_ih,
                     const float* __restrict__ W_hh,
                     const float* __restrict__ b_ih,
                     const float* __restrict__ b_hh,
                     const float* __restrict__ W_out,
                     const float* __restrict__ b_out,
                     float* __restrict__ out)
{
    const int b    = blockIdx.x;
    const int lane = threadIdx.x;
    const int j    = lane & 31;
    const bool upper = (lane >= 32);

    // torch gate order in W_ih/W_hh rows: [0,32)=i [32,64)=f [64,96)=g [96,128)=o
    const int rowA = upper ? (32 + j) : j;        // f : i   (both sigmoid)
    const int rowB = upper ? (96 + j) : (64 + j); // o : g   (sigmoid : tanh)

    // W rows as float2 pairs (raw values)
    f2 Wa2[16], Wb2[16];
    const f2* ra2 = reinterpret_cast<const f2*>(W_hh + (size_t)rowA * HID);
    const f2* rb2 = reinterpret_cast<const f2*>(W_hh + (size_t)rowB * HID);
    #pragma unroll
    for (int q = 0; q < 16; ++q) { Wa2[q] = ra2[q]; Wb2[q] = rb2[q]; }
    // Pin: with the (1,1) clamp the allocator has 512 regs — keep all 32
    // f2 weight pairs resident for the whole kernel.
    #pragma unroll
    for (int q = 0; q < 16; ++q) { asm("" : "+v"(Wa2[q]), "+v"(Wb2[q])); }

    const float wihA = W_ih[rowA];
    const float wihB = W_ih[rowB];
    const float bA = b_ih[rowA] + b_hh[rowA];
    const float bB = b_ih[rowB] + b_hh[rowB];

    // B-gate activation: r = rcp(1 + exp2(-z*sB)); B = r*mB + aB
    const float sB = upper ? L2E : (2.0f * L2E);
    const float mB = upper ? 1.0f : 2.0f;
    const float aB = upper ? 0.0f : -1.0f;

    const float wout = W_out[j];
    const float bout = b_out[0];

    // phist[s][lane], stride 65: store banks (s+l)%32 conflict-free;
    // flush read phist[l*65+32+k] banks (l+k)%32 conflict-free.
    __shared__ float phist[64 * 65];

    float c = 0.0f, h = 0.0f;   // state lives in upper lanes

    const float* xb = x + (size_t)b * T_LEN;
    float*       yb = out + (size_t)b * T_LEN;

    float xv = xb[lane];  // 64 timesteps of x per lane-chunk

    for (int t0 = 0; t0 < T_LEN; t0 += 64) {
        float xv_next = (t0 + 64 < T_LEN) ? xb[t0 + 64 + lane] : 0.0f;

        #pragma unroll 4
        for (int s = 0; s < 64; ++s) {
            // x contribution: independent of h, schedules off-chain
            const float xs  = rlane(xv, s);
            const float xpA = fmaf(xs, wihA, bA);
            const float xpB = fmaf(xs, wihB, bB);

            // Fused broadcast+dot: per q, read h pair from upper lanes (h is
            // the PREVIOUS step's value, loop-carried), pack to an SGPR pair,
            // consume immediately in v_pk_fma. First 4 q's start the split
            // accumulators with v_pk_mul (no zero-init movs).
            f2 zA[4], zB[4];
            #pragma unroll
            for (int q = 0; q < 16; ++q) {
                const unsigned lo = rlane_u(h, 32 + 2 * q);
                const unsigned hi = rlane_u(h, 33 + 2 * q);
                const unsigned long long hp =
                    (unsigned long long)lo | ((unsigned long long)hi << 32);
                if (q < 4) {
                    asm("v_pk_mul_f32 %0, %1, %2"
                        : "=v"(zA[q]) : "s"(hp), "v"(Wa2[q]));
                    asm("v_pk_mul_f32 %0, %1, %2"
                        : "=v"(zB[q]) : "s"(hp), "v"(Wb2[q]));
                } else {
                    asm("v_pk_fma_f32 %0, %1, %2, %0"
                        : "+v"(zA[q & 3]) : "s"(hp), "v"(Wa2[q]));
                    asm("v_pk_fma_f32 %0, %1, %2, %0"
                        : "+v"(zB[q & 3]) : "s"(hp), "v"(Wb2[q]));
                }
            }
            const f2 rA = (zA[0] + zA[1]) + (zA[2] + zA[3]);
            const f2 rB = (zB[0] + zB[1]) + (zB[2] + zB[3]);
            const float za = (rA.x + rA.y) + xpA;
            const float zb = (rB.x + rB.y) + xpB;

            // A = sigmoid(za)  (i on lower, f on upper)
            const float A  = RCPF(1.0f + EXP2F(-za * L2E));
            const float r  = RCPF(1.0f + EXP2F(-zb * sB));
            const float Bv = fmaf(r, mB, aB);  // tanh(g) : sigmoid(o)

            const float u  = A * Bv;           // sig(i)*tanh(g) (lower)
            const float tu = xhalf_lo_to_hi(u);

            c = fmaf(A, c, tu);                // sig(f)*c + u (upper lanes valid)
            const float th = fmaf(2.0f, RCPF(1.0f + EXP2F(-2.0f * L2E * c)), -1.0f);
            h = Bv * th;                       // sig(o)*tanh(c)

            phist[s * 65 + lane] = h * wout;   // unconditional, conflict-free
        }

        __syncthreads();  // single wave: cheap; publish phist
        float acc = bout;
        #pragma unroll
        for (int k = 0; k < HID; ++k) acc += phist[lane * 65 + 32 + k];
        yb[t0 + lane] = acc;
        __syncthreads();  // protect phist before next chunk rewrites it

        xv = xv_next;
    }
}

extern "C" void kernel_launch(void* const* d_in, const int* in_sizes, int n_in,
                              void* d_out, int out_size, void* d_ws, size_t ws_size,
                              hipStream_t stream) {
    const float* x     = (const float*)d_in[0];
    const float* W_ih  = (const float*)d_in[1];
    const float* W_hh  = (const float*)d_in[2];
    const float* b_ih  = (const float*)d_in[3];
    const float* b_hh  = (const float*)d_in[4];
    const float* W_out = (const float*)d_in[5];
    const float* b_out = (const float*)d_in[6];
    float* out = (float*)d_out;

    lstm_seq_kernel<<<BATCH, 64, 0, stream>>>(x, W_ih, W_hh, b_ih, b_hh,
                                              W_out, b_out, out);
}